// Round 7
// baseline (284.456 us; speedup 1.0000x reference)
//
#include <hip/hip_runtime.h>
#include <hip/hip_bf16.h>
#include <stdint.h>

#define D_MODEL 1024
#define NHEADS  16
#define DKH     64
#define BATCH   2
#define SEQ     2048
#define MTOT    (BATCH*SEQ)   // 4096

typedef __attribute__((ext_vector_type(8))) short bf16x8;   // 8 bf16 = 4 VGPRs
typedef __attribute__((ext_vector_type(4))) float f32x4;

__device__ inline unsigned short f2bf(float f) {
    __hip_bfloat16 h = __float2bfloat16(f);
    return *reinterpret_cast<unsigned short*>(&h);
}

// async global->LDS, 16B per lane; LDS dest = wave-uniform base + lane*16 (m97/m104)
__device__ inline void gl2lds16(const unsigned short* g, unsigned short* l) {
    __builtin_amdgcn_global_load_lds(
        (const __attribute__((address_space(1))) void*)g,
        (__attribute__((address_space(3))) void*)l,
        16, 0, 0);
}

// One-shot fp32 -> bf16 conversion of x and the 4 weight matrices.
__global__ __launch_bounds__(256) void cvt_all(
    const float* __restrict__ x,  const float* __restrict__ wq,
    const float* __restrict__ wk, const float* __restrict__ wv,
    const float* __restrict__ wo,
    unsigned short* __restrict__ xb,  unsigned short* __restrict__ wqb,
    unsigned short* __restrict__ wkb, unsigned short* __restrict__ wvb,
    unsigned short* __restrict__ wob)
{
    int bid = blockIdx.x;
    const float* s; unsigned short* d; size_t base;
    if (bid < 2048) { s = x; d = xb; base = (size_t)bid * 2048; }
    else {
        int w  = (bid - 2048) >> 9;
        int wb = (bid - 2048) & 511;
        s = (w == 0) ? wq : (w == 1) ? wk : (w == 2) ? wv : wo;
        d = (w == 0) ? wqb : (w == 1) ? wkb : (w == 2) ? wvb : wob;
        base = (size_t)wb * 2048;
    }
    size_t i = base + (size_t)threadIdx.x * 8;
    float4 a = *(const float4*)(s + i);
    float4 b = *(const float4*)(s + i + 4);
    unsigned short t8[8] = {f2bf(a.x), f2bf(a.y), f2bf(a.z), f2bf(a.w),
                            f2bf(b.x), f2bf(b.y), f2bf(b.z), f2bf(b.w)};
    *(uint4*)(d + i) = *(uint4*)t8;
}

// Vb (MTOT, D_MODEL) bf16 -> VtG [(b*16+h)*64+dk][s] via LDS tile.
__global__ __launch_bounds__(256) void vtrans_kernel(
    const unsigned short* __restrict__ Vb, unsigned short* __restrict__ VtG)
{
    __shared__ __align__(16) unsigned short T[64 * 72];
    const int st = blockIdx.x;
    const int bh = blockIdx.y;
    const int b  = bh >> 4, h = bh & 15;
    const int t  = threadIdx.x;
    const int r  = t >> 2, c = (t & 3) * 16;

    const unsigned short* src = Vb + (size_t)(b * SEQ + st * 64 + r) * D_MODEL + h * DKH + c;
    *(uint4*)(T + r * 72 + c)     = *(const uint4*)(src);
    *(uint4*)(T + r * 72 + c + 8) = *(const uint4*)(src + 8);
    __syncthreads();

    unsigned short tmp[16];
    #pragma unroll
    for (int i = 0; i < 16; ++i) tmp[i] = T[(c + i) * 72 + r];
    unsigned short* dst = VtG + (size_t)(bh * DKH + r) * SEQ + st * 64 + c;
    *(uint4*)(dst)     = *(uint4*)tmp;
    *(uint4*)(dst + 8) = *(uint4*)(tmp + 8);
}

// C[M,N] = scale * A[M,K] @ W[N,K]^T ; bf16 in, fp32 accum, C bf16 or fp32.
// BK=64 as two m97-style BK=32 sub-tiles (unpadded 128x32, global_load_lds w=16).
template<bool CF32>
__global__ __launch_bounds__(256) void gemm_bt(
    const unsigned short* __restrict__ A,
    const unsigned short* __restrict__ W0,
    const unsigned short* __restrict__ W1,
    const unsigned short* __restrict__ W2,
    void* __restrict__ C0, void* __restrict__ C1, void* __restrict__ C2,
    int M, int N, int K, float scale0)
{
    const unsigned short* W = (blockIdx.z == 0) ? W0 : (blockIdx.z == 1 ? W1 : W2);
    void*                 C = (blockIdx.z == 0) ? C0 : (blockIdx.z == 1 ? C1 : C2);
    const float scl = (blockIdx.z == 0) ? scale0 : 1.0f;

    __shared__ __align__(16) unsigned short As[2][128 * 32];
    __shared__ __align__(16) unsigned short Bs[2][128 * 32];

    const int t    = threadIdx.x;
    const int wave = t >> 6, lane = t & 63;
    const int quad = lane >> 4, l16 = lane & 15;
    const int wm   = (wave >> 1) * 64, wn = (wave & 1) * 64;
    const int m0   = blockIdx.x * 128, n0 = blockIdx.y * 128;

    const int srow = lane >> 2;
    const int schk = (lane & 3) * 8;   // shorts
    const unsigned short* Ag = A + (size_t)(m0 + wave * 32 + srow) * K + schk;
    const unsigned short* Wg = W + (size_t)(n0 + wave * 32 + srow) * K + schk;
    const size_t rstep = (size_t)16 * K;
    unsigned short* AsB0 = &As[0][0] + wave * 1024;
    unsigned short* BsB0 = &Bs[0][0] + wave * 1024;

    f32x4 acc[4][4] = {};

    for (int k0 = 0; k0 < K; k0 += 64) {
        __syncthreads();
        #pragma unroll
        for (int s = 0; s < 2; ++s) {
            gl2lds16(Ag + k0 + s * 32,         AsB0 + s * 4096);
            gl2lds16(Ag + k0 + s * 32 + rstep, AsB0 + s * 4096 + 512);
            gl2lds16(Wg + k0 + s * 32,         BsB0 + s * 4096);
            gl2lds16(Wg + k0 + s * 32 + rstep, BsB0 + s * 4096 + 512);
        }
        __syncthreads();

        #pragma unroll
        for (int s = 0; s < 2; ++s) {
            bf16x8 afr[4], bfr[4];
            #pragma unroll
            for (int i = 0; i < 4; ++i) {
                afr[i] = *(const bf16x8*)(&As[s][0] + (wm + i * 16 + l16) * 32 + quad * 8);
                bfr[i] = *(const bf16x8*)(&Bs[s][0] + (wn + i * 16 + l16) * 32 + quad * 8);
            }
            #pragma unroll
            for (int i = 0; i < 4; ++i)
                #pragma unroll
                for (int j = 0; j < 4; ++j)
                    acc[i][j] = __builtin_amdgcn_mfma_f32_16x16x32_bf16(afr[i], bfr[j], acc[i][j], 0, 0, 0);
        }
    }

    #pragma unroll
    for (int i = 0; i < 4; ++i)
        #pragma unroll
        for (int j = 0; j < 4; ++j)
            #pragma unroll
            for (int r = 0; r < 4; ++r) {
                int row = m0 + wm + i * 16 + quad * 4 + r;
                int col = n0 + wn + j * 16 + l16;
                float v = acc[i][j][r] * scl;
                if (CF32) ((float*)C)[(size_t)row * N + col] = v;
                else      ((unsigned short*)C)[(size_t)row * N + col] = f2bf(v);
            }
}

// Flash causal attention, fixed-m softmax, l via ones-column MFMA.
// NO LDS for K/V: B-operand fragments gathered directly from global
// (16B/lane, 16 rows x 64B segments -> L1/L2-resident). Zero __syncthreads
// in the k-loop; waves fully independent. Only wave-private Ps LDS remains.
// grid (32=b*h, 32=qt heavy-first), block 256; wave w: q rows [qt*64+w*16,+16).
__global__ __launch_bounds__(256) void attn_kernel(
    const unsigned short* __restrict__ Qm,
    const unsigned short* __restrict__ Km,
    const unsigned short* __restrict__ VtG,
    unsigned short* __restrict__ Om)
{
    const int bh = blockIdx.x;
    const int qt = 31 - blockIdx.y;             // heavy tiles dispatch first (LPT)
    const int h  = bh & 15;
    const int b  = bh >> 4;
    const int t    = threadIdx.x;
    const int wave = t >> 6, lane = t & 63;
    const int quad = lane >> 4, l16 = lane & 15;

    __shared__ __align__(16) unsigned short Ps[4][16 * 68];   // wave-private P buffer

    const size_t base = (size_t)b * SEQ * D_MODEL + (size_t)h * DKH;
    const unsigned short* Qh = Qm + base;
    const unsigned short* Vh = VtG + (size_t)bh * DKH * SEQ;   // [dk][s]

    // Q A-frags (Q pre-scaled by 1/8 in projection)
    const int qrow = qt * 64 + wave * 16 + l16;
    bf16x8 qf[2];
    qf[0] = *(const bf16x8*)(Qh + (size_t)qrow * D_MODEL + quad * 8);
    qf[1] = *(const bf16x8*)(Qh + (size_t)qrow * D_MODEL + 32 + quad * 8);

    // ones B-frag: B[n][k] = 1 for n==0 else 0 -> D[m][0] = row-sum
    bf16x8 onesf;
    {
        short ov = (l16 == 0) ? (short)0x3F80 : (short)0;
        #pragma unroll
        for (int j = 0; j < 8; ++j) onesf[j] = ov;
    }

    f32x4 accO[4] = {};
    f32x4 accL  = {};

    // per-lane gather bases:
    //  kf(nb,ks): K[(kt*64 + nb*16 + l16)][ks*32 + quad*8]   (16B contiguous in dk)
    //  vf(db,ks): V^T[(db*16 + l16)][kt*64 + ks*32 + quad*8] (16B contiguous in key)
    const unsigned short* Kp = Km + base + (size_t)l16 * D_MODEL + quad * 8;
    const unsigned short* Vp = Vh + (size_t)l16 * SEQ + quad * 8;

    for (int kt = 0; kt <= qt; ++kt) {
        // S = Q K^T ; kf straight from global (L1/L2 hit)
        f32x4 s[4] = {};
        #pragma unroll
        for (int nb = 0; nb < 4; ++nb) {
            const unsigned short* kp = Kp + (size_t)(kt * 64 + nb * 16) * D_MODEL;
            #pragma unroll
            for (int ks = 0; ks < 2; ++ks) {
                bf16x8 kf = *(const bf16x8*)(kp + ks * 32);
                s[nb] = __builtin_amdgcn_mfma_f32_16x16x32_bf16(qf[ks], kf, s[nb], 0, 0, 0);
            }
        }

        // causal mask only on the diagonal tile
        if (kt == qt) {
            const int lrow = wave * 16 + quad * 4;
            #pragma unroll
            for (int nb = 0; nb < 4; ++nb)
                #pragma unroll
                for (int r = 0; r < 4; ++r)
                    s[nb][r] = (nb * 16 + l16 <= lrow + r) ? s[nb][r] : -1e30f;
        }

        // p = exp(s); C-layout -> Ps -> A-layout (wave-private: lgkmcnt only)
        unsigned short* Pw = &Ps[wave][0];
        #pragma unroll
        for (int nb = 0; nb < 4; ++nb)
            #pragma unroll
            for (int r = 0; r < 4; ++r)
                Pw[(quad * 4 + r) * 68 + nb * 16 + l16] = f2bf(__expf(s[nb][r]));
        __builtin_amdgcn_s_waitcnt(0xC07F);   // lgkmcnt(0)

        bf16x8 pf[2];
        pf[0] = *(const bf16x8*)(Pw + l16 * 68 + quad * 8);
        pf[1] = *(const bf16x8*)(Pw + l16 * 68 + 32 + quad * 8);

        // O += P V ; vf straight from global
        #pragma unroll
        for (int db = 0; db < 4; ++db) {
            const unsigned short* vp = Vp + (size_t)(db * 16) * SEQ + kt * 64;
            #pragma unroll
            for (int ks = 0; ks < 2; ++ks) {
                bf16x8 vf = *(const bf16x8*)(vp + ks * 32);
                accO[db] = __builtin_amdgcn_mfma_f32_16x16x32_bf16(pf[ks], vf, accO[db], 0, 0, 0);
            }
        }
        accL = __builtin_amdgcn_mfma_f32_16x16x32_bf16(pf[0], onesf, accL, 0, 0, 0);
        accL = __builtin_amdgcn_mfma_f32_16x16x32_bf16(pf[1], onesf, accL, 0, 0, 0);
    }

    // epilogue: l broadcast (col0 -> quad), divide, store merged (b,l,h*64+dk)
    const int orow0 = b * SEQ + qt * 64 + wave * 16 + quad * 4;
    const int ocol0 = h * DKH + l16;
    #pragma unroll
    for (int r = 0; r < 4; ++r) {
        float l_r = __shfl(accL[r], (lane & 48), 64);   // src lane = quad*16
        float inv = 1.f / l_r;
        #pragma unroll
        for (int db = 0; db < 4; ++db)
            Om[(size_t)(orow0 + r) * D_MODEL + ocol0 + db * 16] = f2bf(accO[db][r] * inv);
    }
}

extern "C" void kernel_launch(void* const* d_in, const int* in_sizes, int n_in,
                              void* d_out, int out_size, void* d_ws, size_t ws_size,
                              hipStream_t stream) {
    const float* x   = (const float*)d_in[0];
    const float* w_q = (const float*)d_in[1];
    const float* w_k = (const float*)d_in[2];
    const float* w_v = (const float*)d_in[3];
    const float* w_o = (const float*)d_in[4];
    float* out = (float*)d_out;

    unsigned short* xb  = (unsigned short*)d_ws;
    unsigned short* VtG = xb;                                  // alias: xb dead after QKV gemm
    unsigned short* wqb = xb  + (size_t)MTOT * D_MODEL;
    unsigned short* wkb = wqb + (size_t)D_MODEL * D_MODEL;
    unsigned short* wvb = wkb + (size_t)D_MODEL * D_MODEL;
    unsigned short* wob = wvb + (size_t)D_MODEL * D_MODEL;
    unsigned short* Qb  = wob + (size_t)D_MODEL * D_MODEL;
    unsigned short* Kb  = Qb  + (size_t)MTOT * D_MODEL;
    unsigned short* Vb  = Kb  + (size_t)MTOT * D_MODEL;
    unsigned short* Ab  = Vb  + (size_t)MTOT * D_MODEL;

    dim3 blk(256);
    cvt_all<<<dim3(2048 + 4 * 512), blk, 0, stream>>>(
        x, w_q, w_k, w_v, w_o, xb, wqb, wkb, wvb, wob);
    gemm_bt<false><<<dim3(MTOT / 128, D_MODEL / 128, 3), blk, 0, stream>>>(
        xb, wqb, wkb, wvb, Qb, Kb, Vb, MTOT, D_MODEL, D_MODEL, 0.125f);
    vtrans_kernel<<<dim3(SEQ / 64, BATCH * NHEADS), blk, 0, stream>>>(Vb, VtG);
    attn_kernel<<<dim3(BATCH * NHEADS, 32), blk, 0, stream>>>(Qb, Kb, VtG, Ab);
    gemm_bt<true><<<dim3(MTOT / 128, D_MODEL / 128, 1), blk, 0, stream>>>(
        Ab, wob, wob, wob, out, out, out, MTOT, D_MODEL, D_MODEL, 1.0f);
}

// Round 8
// 186.221 us; speedup vs baseline: 1.5275x; 1.5275x over previous
//
#include <hip/hip_runtime.h>
#include <hip/hip_bf16.h>
#include <stdint.h>

#define D_MODEL 1024
#define NHEADS  16
#define DKH     64
#define BATCH   2
#define SEQ     2048
#define MTOT    (BATCH*SEQ)   // 4096

typedef __attribute__((ext_vector_type(8))) short bf16x8;   // 8 bf16 = 4 VGPRs
typedef __attribute__((ext_vector_type(4))) float f32x4;

__device__ inline unsigned short f2bf(float f) {
    __hip_bfloat16 h = __float2bfloat16(f);
    return *reinterpret_cast<unsigned short*>(&h);
}

// async global->LDS, 16B per lane; LDS dest = wave-uniform base + lane*16 (m97/m104)
__device__ inline void gl2lds16(const unsigned short* g, unsigned short* l) {
    __builtin_amdgcn_global_load_lds(
        (const __attribute__((address_space(1))) void*)g,
        (__attribute__((address_space(3))) void*)l,
        16, 0, 0);
}

// One-shot fp32 -> bf16 conversion of x and the 4 weight matrices.
__global__ __launch_bounds__(256) void cvt_all(
    const float* __restrict__ x,  const float* __restrict__ wq,
    const float* __restrict__ wk, const float* __restrict__ wv,
    const float* __restrict__ wo,
    unsigned short* __restrict__ xb,  unsigned short* __restrict__ wqb,
    unsigned short* __restrict__ wkb, unsigned short* __restrict__ wvb,
    unsigned short* __restrict__ wob)
{
    int bid = blockIdx.x;
    const float* s; unsigned short* d; size_t base;
    if (bid < 2048) { s = x; d = xb; base = (size_t)bid * 2048; }
    else {
        int w  = (bid - 2048) >> 9;
        int wb = (bid - 2048) & 511;
        s = (w == 0) ? wq : (w == 1) ? wk : (w == 2) ? wv : wo;
        d = (w == 0) ? wqb : (w == 1) ? wkb : (w == 2) ? wvb : wob;
        base = (size_t)wb * 2048;
    }
    size_t i = base + (size_t)threadIdx.x * 8;
    float4 a = *(const float4*)(s + i);
    float4 b = *(const float4*)(s + i + 4);
    unsigned short t8[8] = {f2bf(a.x), f2bf(a.y), f2bf(a.z), f2bf(a.w),
                            f2bf(b.x), f2bf(b.y), f2bf(b.z), f2bf(b.w)};
    *(uint4*)(d + i) = *(uint4*)t8;
}

// C[M,N] = scale * A[M,K] @ W[N,K]^T ; bf16 in, fp32 accum, C bf16 or fp32.
// BK=64 as two m97-style BK=32 sub-tiles (unpadded 128x32, global_load_lds w=16).
// VSWAP: for blockIdx.z==2 swap A<->W2 and x<->y tiles, computing C = W2 @ A^T
// (used to emit V^T = Wv @ x^T directly, fusing the V transpose into the GEMM).
template<bool CF32, bool VSWAP>
__global__ __launch_bounds__(256) void gemm_bt(
    const unsigned short* __restrict__ A,
    const unsigned short* __restrict__ W0,
    const unsigned short* __restrict__ W1,
    const unsigned short* __restrict__ W2,
    void* __restrict__ C0, void* __restrict__ C1, void* __restrict__ C2,
    int M, int N, int K, float scale0)
{
    const bool sw = VSWAP && (blockIdx.z == 2);
    const unsigned short* Aeff = sw ? W2 : A;
    const unsigned short* Weff = (blockIdx.z == 0) ? W0 : (blockIdx.z == 1 ? W1 : (sw ? A : W2));
    void* C = (blockIdx.z == 0) ? C0 : (blockIdx.z == 1 ? C1 : C2);
    const int Neff = sw ? M : N;
    const float scl = (blockIdx.z == 0) ? scale0 : 1.0f;
    const int m0 = (sw ? blockIdx.y : blockIdx.x) * 128;
    const int n0 = (sw ? blockIdx.x : blockIdx.y) * 128;

    __shared__ __align__(16) unsigned short As[2][128 * 32];
    __shared__ __align__(16) unsigned short Bs[2][128 * 32];

    const int t    = threadIdx.x;
    const int wave = t >> 6, lane = t & 63;
    const int quad = lane >> 4, l16 = lane & 15;
    const int wm   = (wave >> 1) * 64, wn = (wave & 1) * 64;

    const int srow = lane >> 2;
    const int schk = (lane & 3) * 8;   // shorts
    const unsigned short* Ag = Aeff + (size_t)(m0 + wave * 32 + srow) * K + schk;
    const unsigned short* Wg = Weff + (size_t)(n0 + wave * 32 + srow) * K + schk;
    const size_t rstep = (size_t)16 * K;
    unsigned short* AsB0 = &As[0][0] + wave * 1024;
    unsigned short* BsB0 = &Bs[0][0] + wave * 1024;

    f32x4 acc[4][4] = {};

    for (int k0 = 0; k0 < K; k0 += 64) {
        __syncthreads();
        #pragma unroll
        for (int s = 0; s < 2; ++s) {
            gl2lds16(Ag + k0 + s * 32,         AsB0 + s * 4096);
            gl2lds16(Ag + k0 + s * 32 + rstep, AsB0 + s * 4096 + 512);
            gl2lds16(Wg + k0 + s * 32,         BsB0 + s * 4096);
            gl2lds16(Wg + k0 + s * 32 + rstep, BsB0 + s * 4096 + 512);
        }
        __syncthreads();

        #pragma unroll
        for (int s = 0; s < 2; ++s) {
            bf16x8 afr[4], bfr[4];
            #pragma unroll
            for (int i = 0; i < 4; ++i) {
                afr[i] = *(const bf16x8*)(&As[s][0] + (wm + i * 16 + l16) * 32 + quad * 8);
                bfr[i] = *(const bf16x8*)(&Bs[s][0] + (wn + i * 16 + l16) * 32 + quad * 8);
            }
            #pragma unroll
            for (int i = 0; i < 4; ++i)
                #pragma unroll
                for (int j = 0; j < 4; ++j)
                    acc[i][j] = __builtin_amdgcn_mfma_f32_16x16x32_bf16(afr[i], bfr[j], acc[i][j], 0, 0, 0);
        }
    }

    #pragma unroll
    for (int i = 0; i < 4; ++i)
        #pragma unroll
        for (int j = 0; j < 4; ++j)
            #pragma unroll
            for (int r = 0; r < 4; ++r) {
                int row = m0 + wm + i * 16 + quad * 4 + r;
                int col = n0 + wn + j * 16 + l16;
                float v = acc[i][j][r] * scl;
                if (CF32) ((float*)C)[(size_t)row * Neff + col] = v;
                else      ((unsigned short*)C)[(size_t)row * Neff + col] = f2bf(v);
            }
}

// Flash causal attention, fixed-m softmax (S bounded ~N(0,1): exp safe in fp32),
// l via ones-column MFMA. V^T comes directly from the fused GEMM: [h*64+dk][b*2048+s].
// grid (32=b*h, 32=y), block 256; y->qt table makes every Δy=8 group (the 4 blocks
// a CU receives at launch, grid==4*256 all-resident) sum to exactly 66 k-iters.
__global__ __launch_bounds__(256) void attn_kernel(
    const unsigned short* __restrict__ Qm,
    const unsigned short* __restrict__ Km,
    const unsigned short* __restrict__ VtG,
    unsigned short* __restrict__ Om)
{
    const int bh = blockIdx.x;
    const int y  = blockIdx.y, g = y & 7, sl = y >> 3;
    const int qt = (sl == 0) ? 31 - g : (sl == 1) ? 16 + g : (sl == 2) ? 15 - g : g;
    const int h  = bh & 15;
    const int b  = bh >> 4;
    const int t    = threadIdx.x;
    const int wave = t >> 6, lane = t & 63;
    const int quad = lane >> 4, l16 = lane & 15;

    __shared__ __align__(16) unsigned short Ks[64 * 72];      // K tile [key][dk]
    __shared__ __align__(16) unsigned short Vt[64 * 72];      // V^T tile [dk][key]
    __shared__ __align__(16) unsigned short Ps[4][16 * 68];   // wave-private P buffer

    const size_t base = (size_t)b * SEQ * D_MODEL + (size_t)h * DKH;
    const unsigned short* Qh = Qm + base;
    const unsigned short* Kh = Km + base;
    const unsigned short* Vh = VtG + (size_t)h * DKH * MTOT + (size_t)b * SEQ;  // [dk][m]

    // Q A-frags (Q pre-scaled by log2(e)/8 in projection -> use exp2)
    const int qrow = qt * 64 + wave * 16 + l16;
    bf16x8 qf[2];
    qf[0] = *(const bf16x8*)(Qh + (size_t)qrow * D_MODEL + quad * 8);
    qf[1] = *(const bf16x8*)(Qh + (size_t)qrow * D_MODEL + 32 + quad * 8);

    // ones B-frag: B[n][k] = 1 for n==0 else 0 -> D[m][0] = row-sum
    bf16x8 onesf;
    {
        short ov = (l16 == 0) ? (short)0x3F80 : (short)0;
        #pragma unroll
        for (int j = 0; j < 8; ++j) onesf[j] = ov;
    }

    f32x4 accO[4] = {};
    f32x4 accL  = {};

    const int srow = t >> 2, scol = (t & 3) * 16;

    // prefetch K/V tile 0 into regs
    uint4 kr0, kr1, vr0, vr1;
    {
        const unsigned short* ks = Kh + (size_t)srow * D_MODEL + scol;
        kr0 = *(const uint4*)ks; kr1 = *(const uint4*)(ks + 8);
        const unsigned short* vs = Vh + (size_t)srow * MTOT + scol;
        vr0 = *(const uint4*)vs; vr1 = *(const uint4*)(vs + 8);
    }

    for (int kt = 0; kt <= qt; ++kt) {
        __syncthreads();   // prior iter's frag reads done
        *(uint4*)(Ks + srow * 72 + scol)     = kr0;
        *(uint4*)(Ks + srow * 72 + scol + 8) = kr1;
        *(uint4*)(Vt + srow * 72 + scol)     = vr0;
        *(uint4*)(Vt + srow * 72 + scol + 8) = vr1;
        __syncthreads();

        if (kt < qt) {     // prefetch next tile; overlaps with compute below
            const unsigned short* ks = Kh + (size_t)((kt + 1) * 64 + srow) * D_MODEL + scol;
            kr0 = *(const uint4*)ks; kr1 = *(const uint4*)(ks + 8);
            const unsigned short* vs = Vh + (size_t)srow * MTOT + (kt + 1) * 64 + scol;
            vr0 = *(const uint4*)vs; vr1 = *(const uint4*)(vs + 8);
        }

        // S = Q K^T
        f32x4 s[4] = {};
        #pragma unroll
        for (int nb = 0; nb < 4; ++nb)
            #pragma unroll
            for (int ks = 0; ks < 2; ++ks) {
                bf16x8 kf = *(const bf16x8*)(Ks + (nb * 16 + l16) * 72 + ks * 32 + quad * 8);
                s[nb] = __builtin_amdgcn_mfma_f32_16x16x32_bf16(qf[ks], kf, s[nb], 0, 0, 0);
            }

        // causal mask only on the diagonal tile
        if (kt == qt) {
            const int lrow = wave * 16 + quad * 4;
            #pragma unroll
            for (int nb = 0; nb < 4; ++nb)
                #pragma unroll
                for (int r = 0; r < 4; ++r)
                    s[nb][r] = (nb * 16 + l16 <= lrow + r) ? s[nb][r] : -1e30f;
        }

        // p = exp2(s)  (log2(e) folded into Q scale; fixed m)
        unsigned short* Pw = &Ps[wave][0];
        #pragma unroll
        for (int nb = 0; nb < 4; ++nb)
            #pragma unroll
            for (int r = 0; r < 4; ++r)
                Pw[(quad * 4 + r) * 68 + nb * 16 + l16] = f2bf(exp2f(s[nb][r]));
        __builtin_amdgcn_s_waitcnt(0xC07F);   // lgkmcnt(0): Ps wave-private

        bf16x8 pf[2];
        pf[0] = *(const bf16x8*)(Pw + l16 * 68 + quad * 8);
        pf[1] = *(const bf16x8*)(Pw + l16 * 68 + 32 + quad * 8);

        // O += P V ; l += P * ones
        #pragma unroll
        for (int db = 0; db < 4; ++db)
            #pragma unroll
            for (int ks = 0; ks < 2; ++ks) {
                bf16x8 vf = *(const bf16x8*)(Vt + (db * 16 + l16) * 72 + ks * 32 + quad * 8);
                accO[db] = __builtin_amdgcn_mfma_f32_16x16x32_bf16(pf[ks], vf, accO[db], 0, 0, 0);
            }
        accL = __builtin_amdgcn_mfma_f32_16x16x32_bf16(pf[0], onesf, accL, 0, 0, 0);
        accL = __builtin_amdgcn_mfma_f32_16x16x32_bf16(pf[1], onesf, accL, 0, 0, 0);
    }

    // epilogue: l broadcast (col0 -> quad), divide, store merged (b,l,h*64+dk)
    const int orow0 = b * SEQ + qt * 64 + wave * 16 + quad * 4;
    const int ocol0 = h * DKH + l16;
    #pragma unroll
    for (int r = 0; r < 4; ++r) {
        float l_r = __shfl(accL[r], (lane & 48), 64);   // src lane = quad*16
        float inv = 1.f / l_r;
        #pragma unroll
        for (int db = 0; db < 4; ++db)
            Om[(size_t)(orow0 + r) * D_MODEL + ocol0 + db * 16] = f2bf(accO[db][r] * inv);
    }
}

extern "C" void kernel_launch(void* const* d_in, const int* in_sizes, int n_in,
                              void* d_out, int out_size, void* d_ws, size_t ws_size,
                              hipStream_t stream) {
    const float* x   = (const float*)d_in[0];
    const float* w_q = (const float*)d_in[1];
    const float* w_k = (const float*)d_in[2];
    const float* w_v = (const float*)d_in[3];
    const float* w_o = (const float*)d_in[4];
    float* out = (float*)d_out;

    // ws (48 MB): xb 8 | weights 4x2 | Qb 8 | Kb 8 | VtG 8 | Ab 8
    unsigned short* xb  = (unsigned short*)d_ws;
    unsigned short* wqb = xb  + (size_t)MTOT * D_MODEL;
    unsigned short* wkb = wqb + (size_t)D_MODEL * D_MODEL;
    unsigned short* wvb = wkb + (size_t)D_MODEL * D_MODEL;
    unsigned short* wob = wvb + (size_t)D_MODEL * D_MODEL;
    unsigned short* Qb  = wob + (size_t)D_MODEL * D_MODEL;
    unsigned short* Kb  = Qb  + (size_t)MTOT * D_MODEL;
    unsigned short* VtG = Kb  + (size_t)MTOT * D_MODEL;   // V^T [1024][4096]
    unsigned short* Ab  = VtG + (size_t)MTOT * D_MODEL;

    dim3 blk(256);
    cvt_all<<<dim3(2048 + 4 * 512), blk, 0, stream>>>(
        x, w_q, w_k, w_v, w_o, xb, wqb, wkb, wvb, wob);
    // fused QKV projection; z==2 emits V^T = Wv @ x^T directly (VSWAP).
    // Q scale = (1/8) * log2(e) so attention can use exp2.
    gemm_bt<false, true><<<dim3(MTOT / 128, D_MODEL / 128, 3), blk, 0, stream>>>(
        xb, wqb, wkb, wvb, Qb, Kb, VtG, MTOT, D_MODEL, D_MODEL, 0.125f * 1.44269504f);
    // balanced causal flash attention
    attn_kernel<<<dim3(BATCH * NHEADS, 32), blk, 0, stream>>>(Qb, Kb, VtG, Ab);
    // output projection -> fp32
    gemm_bt<true, false><<<dim3(MTOT / 128, D_MODEL / 128, 1), blk, 0, stream>>>(
        Ab, wob, wob, wob, out, out, out, MTOT, D_MODEL, D_MODEL, 1.0f);
}

// Round 9
// 176.265 us; speedup vs baseline: 1.6138x; 1.0565x over previous
//
#include <hip/hip_runtime.h>
#include <hip/hip_bf16.h>
#include <stdint.h>

#define D_MODEL 1024
#define NHEADS  16
#define DKH     64
#define BATCH   2
#define SEQ     2048
#define MTOT    (BATCH*SEQ)   // 4096

typedef __attribute__((ext_vector_type(8)))  short bf16x8;   // 8 bf16 = 4 VGPRs
typedef __attribute__((ext_vector_type(4)))  float f32x4;
typedef __attribute__((ext_vector_type(16))) float f32x16;

__device__ inline unsigned short f2bf(float f) {
    __hip_bfloat16 h = __float2bfloat16(f);
    return *reinterpret_cast<unsigned short*>(&h);
}

// async global->LDS, 16B per lane; LDS dest = wave-uniform base + lane*16 (m97/m104)
__device__ inline void gl2lds16(const unsigned short* g, unsigned short* l) {
    __builtin_amdgcn_global_load_lds(
        (const __attribute__((address_space(1))) void*)g,
        (__attribute__((address_space(3))) void*)l,
        16, 0, 0);
}

// One-shot fp32 -> bf16 conversion of x and the 4 weight matrices.
__global__ __launch_bounds__(256) void cvt_all(
    const float* __restrict__ x,  const float* __restrict__ wq,
    const float* __restrict__ wk, const float* __restrict__ wv,
    const float* __restrict__ wo,
    unsigned short* __restrict__ xb,  unsigned short* __restrict__ wqb,
    unsigned short* __restrict__ wkb, unsigned short* __restrict__ wvb,
    unsigned short* __restrict__ wob)
{
    int bid = blockIdx.x;
    const float* s; unsigned short* d; size_t base;
    if (bid < 2048) { s = x; d = xb; base = (size_t)bid * 2048; }
    else {
        int w  = (bid - 2048) >> 9;
        int wb = (bid - 2048) & 511;
        s = (w == 0) ? wq : (w == 1) ? wk : (w == 2) ? wv : wo;
        d = (w == 0) ? wqb : (w == 1) ? wkb : (w == 2) ? wvb : wob;
        base = (size_t)wb * 2048;
    }
    size_t i = base + (size_t)threadIdx.x * 8;
    float4 a = *(const float4*)(s + i);
    float4 b = *(const float4*)(s + i + 4);
    unsigned short t8[8] = {f2bf(a.x), f2bf(a.y), f2bf(a.z), f2bf(a.w),
                            f2bf(b.x), f2bf(b.y), f2bf(b.z), f2bf(b.w)};
    *(uint4*)(d + i) = *(uint4*)t8;
}

// C[M,N] = scale * A[M,K] @ W[N,K]^T ; bf16 in, fp32 accum, C bf16 or fp32.
// BK=64 as two m97-style BK=32 sub-tiles (unpadded 128x32, global_load_lds w=16).
// VSWAP: blockIdx.z==2 computes C = W2 @ A^T (emits V^T directly).
template<bool CF32, bool VSWAP>
__global__ __launch_bounds__(256) void gemm_bt(
    const unsigned short* __restrict__ A,
    const unsigned short* __restrict__ W0,
    const unsigned short* __restrict__ W1,
    const unsigned short* __restrict__ W2,
    void* __restrict__ C0, void* __restrict__ C1, void* __restrict__ C2,
    int M, int N, int K, float scale0)
{
    const bool sw = VSWAP && (blockIdx.z == 2);
    const unsigned short* Aeff = sw ? W2 : A;
    const unsigned short* Weff = (blockIdx.z == 0) ? W0 : (blockIdx.z == 1 ? W1 : (sw ? A : W2));
    void* C = (blockIdx.z == 0) ? C0 : (blockIdx.z == 1 ? C1 : C2);
    const int Neff = sw ? M : N;
    const float scl = (blockIdx.z == 0) ? scale0 : 1.0f;
    const int m0 = (sw ? blockIdx.y : blockIdx.x) * 128;
    const int n0 = (sw ? blockIdx.x : blockIdx.y) * 128;

    __shared__ __align__(16) unsigned short As[2][128 * 32];
    __shared__ __align__(16) unsigned short Bs[2][128 * 32];

    const int t    = threadIdx.x;
    const int wave = t >> 6, lane = t & 63;
    const int quad = lane >> 4, l16 = lane & 15;
    const int wm   = (wave >> 1) * 64, wn = (wave & 1) * 64;

    const int srow = lane >> 2;
    const int schk = (lane & 3) * 8;   // shorts
    const unsigned short* Ag = Aeff + (size_t)(m0 + wave * 32 + srow) * K + schk;
    const unsigned short* Wg = Weff + (size_t)(n0 + wave * 32 + srow) * K + schk;
    const size_t rstep = (size_t)16 * K;
    unsigned short* AsB0 = &As[0][0] + wave * 1024;
    unsigned short* BsB0 = &Bs[0][0] + wave * 1024;

    f32x4 acc[4][4] = {};

    for (int k0 = 0; k0 < K; k0 += 64) {
        __syncthreads();
        #pragma unroll
        for (int s = 0; s < 2; ++s) {
            gl2lds16(Ag + k0 + s * 32,         AsB0 + s * 4096);
            gl2lds16(Ag + k0 + s * 32 + rstep, AsB0 + s * 4096 + 512);
            gl2lds16(Wg + k0 + s * 32,         BsB0 + s * 4096);
            gl2lds16(Wg + k0 + s * 32 + rstep, BsB0 + s * 4096 + 512);
        }
        __syncthreads();

        #pragma unroll
        for (int s = 0; s < 2; ++s) {
            bf16x8 afr[4], bfr[4];
            #pragma unroll
            for (int i = 0; i < 4; ++i) {
                afr[i] = *(const bf16x8*)(&As[s][0] + (wm + i * 16 + l16) * 32 + quad * 8);
                bfr[i] = *(const bf16x8*)(&Bs[s][0] + (wn + i * 16 + l16) * 32 + quad * 8);
            }
            #pragma unroll
            for (int i = 0; i < 4; ++i)
                #pragma unroll
                for (int j = 0; j < 4; ++j)
                    acc[i][j] = __builtin_amdgcn_mfma_f32_16x16x32_bf16(afr[i], bfr[j], acc[i][j], 0, 0, 0);
        }
    }

    #pragma unroll
    for (int i = 0; i < 4; ++i)
        #pragma unroll
        for (int j = 0; j < 4; ++j)
            #pragma unroll
            for (int r = 0; r < 4; ++r) {
                int row = m0 + wm + i * 16 + quad * 4 + r;
                int col = n0 + wn + j * 16 + l16;
                float v = acc[i][j][r] * scl;
                if (CF32) ((float*)C)[(size_t)row * Neff + col] = v;
                else      ((unsigned short*)C)[(size_t)row * Neff + col] = f2bf(v);
            }
}

// Flash causal attention, fixed-m softmax, 32x32x16 MFMA, split-key waves.
// q-tile 64 rows/block; wave (qhalf=w>>1, khalf=w&1) computes S[32 q x 32 keys]
// and a partial O over its 32 keys; once-per-block cross-wave reduction merges
// key-halves through the (then dead) Ks/Vt LDS. Cuts LDS frag reads per Q-row
// ~1.8x vs the 16x16 version at identical occupancy (R6/R7 lessons).
// grid (32=b*h, 32=y balanced), block 256.
__global__ __launch_bounds__(256, 4) void attn_kernel(
    const unsigned short* __restrict__ Qm,
    const unsigned short* __restrict__ Km,
    const unsigned short* __restrict__ VtG,
    unsigned short* __restrict__ Om)
{
    const int bh = blockIdx.x;
    const int y  = blockIdx.y, g = y & 7, sl = y >> 3;
    const int qt = (sl == 0) ? 31 - g : (sl == 1) ? 16 + g : (sl == 2) ? 15 - g : g;
    const int h  = bh & 15;
    const int b  = bh >> 4;
    const int t     = threadIdx.x;
    const int wave  = t >> 6, lane = t & 63;
    const int qhalf = wave >> 1, khalf = wave & 1;
    const int l31   = lane & 31, h32 = lane >> 5;

    __shared__ __align__(16) unsigned short Ks[64 * 72];      // K tile [key][dk]
    __shared__ __align__(16) unsigned short Vt[64 * 72];      // V^T tile [dk][key]
    __shared__ __align__(16) unsigned short Ps[4][32 * 40];   // per-wave P [qrow][key_local]

    const size_t base = (size_t)b * SEQ * D_MODEL + (size_t)h * DKH;
    const unsigned short* Qh = Qm + base;
    const unsigned short* Kh = Km + base;
    const unsigned short* Vh = VtG + (size_t)h * DKH * MTOT + (size_t)b * SEQ;  // [dk][m]

    // Q A-frags, 32x32x16: A[m=l31][k=h32*8+j], 4 k-steps cover dk 64.
    const int qrow = qt * 64 + qhalf * 32 + l31;
    bf16x8 qf[4];
    #pragma unroll
    for (int ks = 0; ks < 4; ++ks)
        qf[ks] = *(const bf16x8*)(Qh + (size_t)qrow * D_MODEL + ks * 16 + h32 * 8);

    f32x16 accO[2] = {};      // O partial, C-layout: col=l31(dk), row=(reg&3)+8*(reg>>2)+4*h32
    float  l_acc[16] = {};    // per-lane row-sum partials (summed over lanes at end)

    const int srow = t >> 2, scol = (t & 3) * 16;
    const int kbase = khalf * 32;

    // prefetch K/V tile 0 into regs
    uint4 kr0, kr1, vr0, vr1;
    {
        const unsigned short* ks = Kh + (size_t)srow * D_MODEL + scol;
        kr0 = *(const uint4*)ks; kr1 = *(const uint4*)(ks + 8);
        const unsigned short* vs = Vh + (size_t)srow * MTOT + scol;
        vr0 = *(const uint4*)vs; vr1 = *(const uint4*)(vs + 8);
    }

    for (int kt = 0; kt <= qt; ++kt) {
        __syncthreads();   // prior iter's frag reads done
        *(uint4*)(Ks + srow * 72 + scol)     = kr0;
        *(uint4*)(Ks + srow * 72 + scol + 8) = kr1;
        *(uint4*)(Vt + srow * 72 + scol)     = vr0;
        *(uint4*)(Vt + srow * 72 + scol + 8) = vr1;
        __syncthreads();

        if (kt < qt) {     // prefetch next tile; overlaps compute below
            const unsigned short* ks = Kh + (size_t)((kt + 1) * 64 + srow) * D_MODEL + scol;
            kr0 = *(const uint4*)ks; kr1 = *(const uint4*)(ks + 8);
            const unsigned short* vs = Vh + (size_t)srow * MTOT + (kt + 1) * 64 + scol;
            vr0 = *(const uint4*)vs; vr1 = *(const uint4*)(vs + 8);
        }

        const bool diag = (kt == qt);
        if (diag && khalf > qhalf) continue;   // quarter-tile fully masked: skip (no barriers inside)

        // S = Q K^T : B[n=key=kbase+l31][k=dk], 4 chained 32x32x16
        f32x16 s = {};
        #pragma unroll
        for (int ks = 0; ks < 4; ++ks) {
            bf16x8 kf = *(const bf16x8*)(Ks + (kbase + l31) * 72 + ks * 16 + h32 * 8);
            s = __builtin_amdgcn_mfma_f32_32x32x16_bf16(qf[ks], kf, s, 0, 0, 0);
        }

        // p = exp2(s) (log2e/8 folded into Q); causal mask on equal-half diag quarters
        unsigned short* Pw = &Ps[wave][0];
        const bool maskq = diag && (khalf == qhalf);
        #pragma unroll
        for (int reg = 0; reg < 16; ++reg) {
            const int rloc = (reg & 3) + 8 * (reg >> 2) + 4 * h32;
            float v = s[reg];
            if (maskq) v = (l31 <= rloc) ? v : -1e30f;
            float p = exp2f(v);
            l_acc[reg] += p;
            Pw[rloc * 40 + l31] = f2bf(p);
        }
        __builtin_amdgcn_s_waitcnt(0xC07F);   // lgkmcnt(0): Ps wave-private

        // O += P V : A=P[m=qrow][k=key_local], B=V^T[n=dk][k=key_local]
        #pragma unroll
        for (int ks2 = 0; ks2 < 2; ++ks2) {
            bf16x8 pf = *(const bf16x8*)(Pw + l31 * 40 + ks2 * 16 + h32 * 8);
            #pragma unroll
            for (int db = 0; db < 2; ++db) {
                bf16x8 vf = *(const bf16x8*)(Vt + (db * 32 + l31) * 72 + kbase + ks2 * 16 + h32 * 8);
                accO[db] = __builtin_amdgcn_mfma_f32_32x32x16_bf16(pf, vf, accO[db], 0, 0, 0);
            }
        }
    }

    // ---- cross-wave reduction over key halves (khalf 1 -> 0), through dead Ks/Vt ----
    __syncthreads();   // everyone done with Ks/Vt frags
    float* exO = (qhalf == 0) ? (float*)Ks : (float*)Vt;            // 64 lanes x 36 floats
    float* exL = (float*)(&Ps[0][0]) + (size_t)qhalf * 1280;        // 64 lanes x 20 floats
    if (khalf == 1) {
        #pragma unroll
        for (int db = 0; db < 2; ++db)
            #pragma unroll
            for (int c = 0; c < 4; ++c) {
                float4 v = { accO[db][c*4], accO[db][c*4+1], accO[db][c*4+2], accO[db][c*4+3] };
                *(float4*)(exO + lane * 36 + db * 16 + c * 4) = v;
            }
        #pragma unroll
        for (int c = 0; c < 4; ++c) {
            float4 v = { l_acc[c*4], l_acc[c*4+1], l_acc[c*4+2], l_acc[c*4+3] };
            *(float4*)(exL + lane * 20 + c * 4) = v;
        }
    }
    __syncthreads();
    if (khalf == 0) {
        #pragma unroll
        for (int db = 0; db < 2; ++db)
            #pragma unroll
            for (int c = 0; c < 4; ++c) {
                float4 v = *(const float4*)(exO + lane * 36 + db * 16 + c * 4);
                accO[db][c*4]   += v.x; accO[db][c*4+1] += v.y;
                accO[db][c*4+2] += v.z; accO[db][c*4+3] += v.w;
            }
        #pragma unroll
        for (int c = 0; c < 4; ++c) {
            float4 v = *(const float4*)(exL + lane * 20 + c * 4);
            l_acc[c*4] += v.x; l_acc[c*4+1] += v.y; l_acc[c*4+2] += v.z; l_acc[c*4+3] += v.w;
        }
        // row-sum butterfly over the 32 columns (lanes within the same h32 group)
        #pragma unroll
        for (int off = 1; off < 32; off <<= 1)
            #pragma unroll
            for (int reg = 0; reg < 16; ++reg)
                l_acc[reg] += __shfl_xor(l_acc[reg], off, 64);

        // epilogue: O/l, store merged (b, l, h*64+dk)
        const int orow_base = b * SEQ + qt * 64 + qhalf * 32;
        #pragma unroll
        for (int reg = 0; reg < 16; ++reg) {
            const int rloc = (reg & 3) + 8 * (reg >> 2) + 4 * h32;
            const float inv = 1.f / l_acc[reg];
            #pragma unroll
            for (int db = 0; db < 2; ++db)
                Om[(size_t)(orow_base + rloc) * D_MODEL + h * DKH + db * 32 + l31] =
                    f2bf(accO[db][reg] * inv);
        }
    }
}

extern "C" void kernel_launch(void* const* d_in, const int* in_sizes, int n_in,
                              void* d_out, int out_size, void* d_ws, size_t ws_size,
                              hipStream_t stream) {
    const float* x   = (const float*)d_in[0];
    const float* w_q = (const float*)d_in[1];
    const float* w_k = (const float*)d_in[2];
    const float* w_v = (const float*)d_in[3];
    const float* w_o = (const float*)d_in[4];
    float* out = (float*)d_out;

    // ws (48 MB): xb 8 | weights 4x2 | Qb 8 | Kb 8 | VtG 8 | Ab 8
    unsigned short* xb  = (unsigned short*)d_ws;
    unsigned short* wqb = xb  + (size_t)MTOT * D_MODEL;
    unsigned short* wkb = wqb + (size_t)D_MODEL * D_MODEL;
    unsigned short* wvb = wkb + (size_t)D_MODEL * D_MODEL;
    unsigned short* wob = wvb + (size_t)D_MODEL * D_MODEL;
    unsigned short* Qb  = wob + (size_t)D_MODEL * D_MODEL;
    unsigned short* Kb  = Qb  + (size_t)MTOT * D_MODEL;
    unsigned short* VtG = Kb  + (size_t)MTOT * D_MODEL;   // V^T [1024][4096]
    unsigned short* Ab  = VtG + (size_t)MTOT * D_MODEL;

    dim3 blk(256);
    cvt_all<<<dim3(2048 + 4 * 512), blk, 0, stream>>>(
        x, w_q, w_k, w_v, w_o, xb, wqb, wkb, wvb, wob);
    // fused QKV projection; z==2 emits V^T = Wv @ x^T directly (VSWAP).
    // Q scale = (1/8) * log2(e) so attention can use exp2.
    gemm_bt<false, true><<<dim3(MTOT / 128, D_MODEL / 128, 3), blk, 0, stream>>>(
        xb, wqb, wkb, wvb, Qb, Kb, VtG, MTOT, D_MODEL, D_MODEL, 0.125f * 1.44269504f);
    // balanced causal flash attention (32x32 MFMA, split-key waves)
    attn_kernel<<<dim3(BATCH * NHEADS, 32), blk, 0, stream>>>(Qb, Kb, VtG, Ab);
    // output projection -> fp32
    gemm_bt<true, false><<<dim3(MTOT / 128, D_MODEL / 128, 1), blk, 0, stream>>>(
        Ab, wob, wob, wob, out, out, out, MTOT, D_MODEL, D_MODEL, 1.0f);
}

// Round 10
// 170.559 us; speedup vs baseline: 1.6678x; 1.0335x over previous
//
#include <hip/hip_runtime.h>
#include <hip/hip_bf16.h>
#include <stdint.h>

#define D_MODEL 1024
#define NHEADS  16
#define DKH     64
#define BATCH   2
#define SEQ     2048
#define MTOT    (BATCH*SEQ)   // 4096

typedef __attribute__((ext_vector_type(8)))  short bf16x8;   // 8 bf16 = 4 VGPRs
typedef __attribute__((ext_vector_type(4)))  float f32x4;
typedef __attribute__((ext_vector_type(16))) float f32x16;
typedef __attribute__((ext_vector_type(4)))  unsigned int u32x4;

__device__ inline unsigned short f2bf(float f) {
    __hip_bfloat16 h = __float2bfloat16(f);
    return *reinterpret_cast<unsigned short*>(&h);
}
__device__ inline unsigned int pack2bf(float a, float b) {   // low=a, high=b (RNE)
    __hip_bfloat162 h = __float22bfloat162_rn(float2{a, b});
    return *reinterpret_cast<unsigned int*>(&h);
}

// async global->LDS, 16B per lane; LDS dest = wave-uniform base + lane*16 (m97/m104)
__device__ inline void gl2lds16(const unsigned short* g, unsigned short* l) {
    __builtin_amdgcn_global_load_lds(
        (const __attribute__((address_space(1))) void*)g,
        (__attribute__((address_space(3))) void*)l,
        16, 0, 0);
}

// One-shot fp32 -> bf16 conversion of x and the 4 weight matrices.
__global__ __launch_bounds__(256) void cvt_all(
    const float* __restrict__ x,  const float* __restrict__ wq,
    const float* __restrict__ wk, const float* __restrict__ wv,
    const float* __restrict__ wo,
    unsigned short* __restrict__ xb,  unsigned short* __restrict__ wqb,
    unsigned short* __restrict__ wkb, unsigned short* __restrict__ wvb,
    unsigned short* __restrict__ wob)
{
    int bid = blockIdx.x;
    const float* s; unsigned short* d; size_t base;
    if (bid < 2048) { s = x; d = xb; base = (size_t)bid * 2048; }
    else {
        int w  = (bid - 2048) >> 9;
        int wb = (bid - 2048) & 511;
        s = (w == 0) ? wq : (w == 1) ? wk : (w == 2) ? wv : wo;
        d = (w == 0) ? wqb : (w == 1) ? wkb : (w == 2) ? wvb : wob;
        base = (size_t)wb * 2048;
    }
    size_t i = base + (size_t)threadIdx.x * 8;
    float4 a = *(const float4*)(s + i);
    float4 b = *(const float4*)(s + i + 4);
    unsigned short t8[8] = {f2bf(a.x), f2bf(a.y), f2bf(a.z), f2bf(a.w),
                            f2bf(b.x), f2bf(b.y), f2bf(b.z), f2bf(b.w)};
    *(uint4*)(d + i) = *(uint4*)t8;
}

// C[M,N] = scale * A[M,K] @ W[N,K]^T ; bf16 in, fp32 accum, C bf16 or fp32.
// BK=64 as two m97-style BK=32 sub-tiles (unpadded 128x32, global_load_lds w=16).
// VSWAP: blockIdx.z==2 computes C = W2 @ A^T (emits V^T directly).
template<bool CF32, bool VSWAP>
__global__ __launch_bounds__(256) void gemm_bt(
    const unsigned short* __restrict__ A,
    const unsigned short* __restrict__ W0,
    const unsigned short* __restrict__ W1,
    const unsigned short* __restrict__ W2,
    void* __restrict__ C0, void* __restrict__ C1, void* __restrict__ C2,
    int M, int N, int K, float scale0)
{
    const bool sw = VSWAP && (blockIdx.z == 2);
    const unsigned short* Aeff = sw ? W2 : A;
    const unsigned short* Weff = (blockIdx.z == 0) ? W0 : (blockIdx.z == 1 ? W1 : (sw ? A : W2));
    void* C = (blockIdx.z == 0) ? C0 : (blockIdx.z == 1 ? C1 : C2);
    const int Neff = sw ? M : N;
    const float scl = (blockIdx.z == 0) ? scale0 : 1.0f;
    const int m0 = (sw ? blockIdx.y : blockIdx.x) * 128;
    const int n0 = (sw ? blockIdx.x : blockIdx.y) * 128;

    __shared__ __align__(16) unsigned short As[2][128 * 32];
    __shared__ __align__(16) unsigned short Bs[2][128 * 32];

    const int t    = threadIdx.x;
    const int wave = t >> 6, lane = t & 63;
    const int quad = lane >> 4, l16 = lane & 15;
    const int wm   = (wave >> 1) * 64, wn = (wave & 1) * 64;

    const int srow = lane >> 2;
    const int schk = (lane & 3) * 8;   // shorts
    const unsigned short* Ag = Aeff + (size_t)(m0 + wave * 32 + srow) * K + schk;
    const unsigned short* Wg = Weff + (size_t)(n0 + wave * 32 + srow) * K + schk;
    const size_t rstep = (size_t)16 * K;
    unsigned short* AsB0 = &As[0][0] + wave * 1024;
    unsigned short* BsB0 = &Bs[0][0] + wave * 1024;

    f32x4 acc[4][4] = {};

    for (int k0 = 0; k0 < K; k0 += 64) {
        __syncthreads();
        #pragma unroll
        for (int s = 0; s < 2; ++s) {
            gl2lds16(Ag + k0 + s * 32,         AsB0 + s * 4096);
            gl2lds16(Ag + k0 + s * 32 + rstep, AsB0 + s * 4096 + 512);
            gl2lds16(Wg + k0 + s * 32,         BsB0 + s * 4096);
            gl2lds16(Wg + k0 + s * 32 + rstep, BsB0 + s * 4096 + 512);
        }
        __syncthreads();

        #pragma unroll
        for (int s = 0; s < 2; ++s) {
            bf16x8 afr[4], bfr[4];
            #pragma unroll
            for (int i = 0; i < 4; ++i) {
                afr[i] = *(const bf16x8*)(&As[s][0] + (wm + i * 16 + l16) * 32 + quad * 8);
                bfr[i] = *(const bf16x8*)(&Bs[s][0] + (wn + i * 16 + l16) * 32 + quad * 8);
            }
            #pragma unroll
            for (int i = 0; i < 4; ++i)
                #pragma unroll
                for (int j = 0; j < 4; ++j)
                    acc[i][j] = __builtin_amdgcn_mfma_f32_16x16x32_bf16(afr[i], bfr[j], acc[i][j], 0, 0, 0);
        }
    }

    #pragma unroll
    for (int i = 0; i < 4; ++i)
        #pragma unroll
        for (int j = 0; j < 4; ++j)
            #pragma unroll
            for (int r = 0; r < 4; ++r) {
                int row = m0 + wm + i * 16 + quad * 4 + r;
                int col = n0 + wn + j * 16 + l16;
                float v = acc[i][j][r] * scl;
                if (CF32) ((float*)C)[(size_t)row * Neff + col] = v;
                else      ((unsigned short*)C)[(size_t)row * Neff + col] = f2bf(v);
            }
}

// Flash causal attention, fixed-m softmax, 32x32x16 MFMA, split-key waves,
// TRANSPOSED inner products: S^T = K·Q^T, O^T = V^T·P^T. A lane then owns a
// single q (=l31), so (a) l is a scalar accumulator, (b) the PV B-operand P^T
// is built in registers via one half-wave shfl_xor(32) exchange — no P LDS
// round-trip, no per-iter lgkmcnt(0) drain. O^T is transposed back through
// the dead Ks LDS once per block for coalesced stores.
// grid (32=b*h, 32=y balanced), block 256.
__global__ __launch_bounds__(256, 4) void attn_kernel(
    const unsigned short* __restrict__ Qm,
    const unsigned short* __restrict__ Km,
    const unsigned short* __restrict__ VtG,
    unsigned short* __restrict__ Om)
{
    const int bh = blockIdx.x;
    const int y  = blockIdx.y, g = y & 7, sl = y >> 3;
    const int qt = (sl == 0) ? 31 - g : (sl == 1) ? 16 + g : (sl == 2) ? 15 - g : g;
    const int h  = bh & 15;
    const int b  = bh >> 4;
    const int t     = threadIdx.x;
    const int wave  = t >> 6, lane = t & 63;
    const int qhalf = wave >> 1, khalf = wave & 1;
    const int l31   = lane & 31, h32 = lane >> 5;

    __shared__ __align__(16) unsigned short Ks[64 * 72];      // K tile [key][dk]
    __shared__ __align__(16) unsigned short Vt[64 * 72];      // V^T tile [dk][key]

    const size_t base = (size_t)b * SEQ * D_MODEL + (size_t)h * DKH;
    const unsigned short* Qh = Qm + base;
    const unsigned short* Kh = Km + base;
    const unsigned short* Vh = VtG + (size_t)h * DKH * MTOT + (size_t)b * SEQ;  // [dk][m]

    // Q B-frags (Q pre-scaled by log2e/8): B[n=q=l31][k=h32*8+j], 4 k-steps = dk 64
    const int qrow = qt * 64 + qhalf * 32 + l31;
    bf16x8 qf[4];
    #pragma unroll
    for (int ks = 0; ks < 4; ++ks)
        qf[ks] = *(const bf16x8*)(Qh + (size_t)qrow * D_MODEL + ks * 16 + h32 * 8);

    f32x16 accOT[2] = {};   // O^T partial: col=l31=q, row=(reg&3)+8*(reg>>2)+4*h32=dk (+32*db)
    float  l_s = 0.f;       // scalar row-sum partial (q=l31, this lane's 16 keys)

    const int srow = t >> 2, scol = (t & 3) * 16;
    const int kbase = khalf * 32;

    // prefetch K/V tile 0 into regs
    uint4 kr0, kr1, vr0, vr1;
    {
        const unsigned short* ks = Kh + (size_t)srow * D_MODEL + scol;
        kr0 = *(const uint4*)ks; kr1 = *(const uint4*)(ks + 8);
        const unsigned short* vs = Vh + (size_t)srow * MTOT + scol;
        vr0 = *(const uint4*)vs; vr1 = *(const uint4*)(vs + 8);
    }

    for (int kt = 0; kt <= qt; ++kt) {
        __syncthreads();   // prior iter's frag reads done
        *(uint4*)(Ks + srow * 72 + scol)     = kr0;
        *(uint4*)(Ks + srow * 72 + scol + 8) = kr1;
        *(uint4*)(Vt + srow * 72 + scol)     = vr0;
        *(uint4*)(Vt + srow * 72 + scol + 8) = vr1;
        __syncthreads();

        if (kt < qt) {     // prefetch next tile; overlaps compute below
            const unsigned short* ks = Kh + (size_t)((kt + 1) * 64 + srow) * D_MODEL + scol;
            kr0 = *(const uint4*)ks; kr1 = *(const uint4*)(ks + 8);
            const unsigned short* vs = Vh + (size_t)srow * MTOT + (kt + 1) * 64 + scol;
            vr0 = *(const uint4*)vs; vr1 = *(const uint4*)(vs + 8);
        }

        const bool diag = (kt == qt);
        if (diag && khalf > qhalf) continue;   // fully-masked quarter: skip

        // S^T = K Q^T : A=K rows (same LDS bytes as before, roles swapped)
        f32x16 sT = {};
        #pragma unroll
        for (int ks = 0; ks < 4; ++ks) {
            bf16x8 kf = *(const bf16x8*)(Ks + (kbase + l31) * 72 + ks * 16 + h32 * 8);
            sT = __builtin_amdgcn_mfma_f32_32x32x16_bf16(kf, qf[ks], sT, 0, 0, 0);
        }

        // p = exp2(s); mask on equal-half diag quarter: keep key(rloc) <= q(l31)
        const bool maskq = diag && (khalf == qhalf);
        float pv[16];
        #pragma unroll
        for (int reg = 0; reg < 16; ++reg) {
            const int rloc = (reg & 3) + 8 * (reg >> 2) + 4 * h32;   // key_local
            float v = sT[reg];
            if (maskq) v = (rloc <= l31) ? v : -1e30f;
            float p = exp2f(v);
            l_s += p;
            pv[reg] = p;
        }
        // pack pairs (consecutive regs = consecutive keys) and half-wave exchange
        unsigned int pk[8], pr[8];
        #pragma unroll
        for (int i = 0; i < 8; ++i) pk[i] = pack2bf(pv[2 * i], pv[2 * i + 1]);
        #pragma unroll
        for (int i = 0; i < 8; ++i) pr[i] = __shfl_xor(pk[i], 32, 64);

        // O^T += V^T P^T : A = V^T rows (same bytes as before), B = P^T in regs
        #pragma unroll
        for (int ks2 = 0; ks2 < 2; ++ks2) {
            union { u32x4 u; bf16x8 b; } pf;
            pf.u[0] = h32 ? pr[4 * ks2 + 2] : pk[4 * ks2 + 0];
            pf.u[1] = h32 ? pr[4 * ks2 + 3] : pk[4 * ks2 + 1];
            pf.u[2] = h32 ? pk[4 * ks2 + 2] : pr[4 * ks2 + 0];
            pf.u[3] = h32 ? pk[4 * ks2 + 3] : pr[4 * ks2 + 1];
            #pragma unroll
            for (int db = 0; db < 2; ++db) {
                bf16x8 vf = *(const bf16x8*)(Vt + (db * 32 + l31) * 72 + kbase + ks2 * 16 + h32 * 8);
                accOT[db] = __builtin_amdgcn_mfma_f32_32x32x16_bf16(vf, pf.b, accOT[db], 0, 0, 0);
            }
        }
    }

    // ---- merge key halves (khalf 1 -> 0) through dead Ks/Vt ----
    __syncthreads();
    float* exO = (qhalf == 0) ? (float*)Ks : (float*)Vt;   // 64 lanes x 36 floats (32 O + l + pad)
    if (khalf == 1) {
        #pragma unroll
        for (int db = 0; db < 2; ++db)
            #pragma unroll
            for (int c = 0; c < 4; ++c) {
                float4 v = { accOT[db][c*4], accOT[db][c*4+1], accOT[db][c*4+2], accOT[db][c*4+3] };
                *(float4*)(exO + lane * 36 + db * 16 + c * 4) = v;
            }
        exO[lane * 36 + 32] = l_s;
    }
    __syncthreads();
    float inv = 0.f;
    if (khalf == 0) {
        #pragma unroll
        for (int db = 0; db < 2; ++db)
            #pragma unroll
            for (int c = 0; c < 4; ++c) {
                float4 v = *(const float4*)(exO + lane * 36 + db * 16 + c * 4);
                accOT[db][c*4]   += v.x; accOT[db][c*4+1] += v.y;
                accOT[db][c*4+2] += v.z; accOT[db][c*4+3] += v.w;
            }
        l_s += exO[lane * 36 + 32];
        l_s += __shfl_xor(l_s, 32, 64);   // other h32 half of the same q
        inv = 1.f / l_s;
    }
    __syncthreads();   // merge reads done; Ks free for the transpose tile

    // ---- transpose O^T -> [q][dk] bf16 tile in Ks, then coalesced store ----
    unsigned short* Ot = Ks;   // [64][68] u16
    if (khalf == 0) {
        const int row = qhalf * 32 + l31;
        #pragma unroll
        for (int db = 0; db < 2; ++db)
            #pragma unroll
            for (int c = 0; c < 4; ++c) {
                // dk pairs: (8c+4*h32, +1) and (+2, +3)
                unsigned int w0 = pack2bf(accOT[db][4*c]   * inv, accOT[db][4*c+1] * inv);
                unsigned int w1 = pack2bf(accOT[db][4*c+2] * inv, accOT[db][4*c+3] * inv);
                const int off = db * 32 + 8 * c + 4 * h32;
                *(unsigned int*)(Ot + row * 68 + off)     = w0;
                *(unsigned int*)(Ot + row * 68 + off + 2) = w1;
            }
    }
    __syncthreads();
    {
        const int row = t >> 2, col = (t & 3) * 16;
        uint4 o0 = *(const uint4*)(Ot + row * 68 + col);
        uint4 o1 = *(const uint4*)(Ot + row * 68 + col + 8);
        unsigned short* dst = Om + (size_t)(b * SEQ + qt * 64 + row) * D_MODEL + h * DKH + col;
        *(uint4*)(dst)     = o0;
        *(uint4*)(dst + 8) = o1;
    }
}

extern "C" void kernel_launch(void* const* d_in, const int* in_sizes, int n_in,
                              void* d_out, int out_size, void* d_ws, size_t ws_size,
                              hipStream_t stream) {
    const float* x   = (const float*)d_in[0];
    const float* w_q = (const float*)d_in[1];
    const float* w_k = (const float*)d_in[2];
    const float* w_v = (const float*)d_in[3];
    const float* w_o = (const float*)d_in[4];
    float* out = (float*)d_out;

    // ws (48 MB): xb 8 | weights 4x2 | Qb 8 | Kb 8 | VtG 8 | Ab 8
    unsigned short* xb  = (unsigned short*)d_ws;
    unsigned short* wqb = xb  + (size_t)MTOT * D_MODEL;
    unsigned short* wkb = wqb + (size_t)D_MODEL * D_MODEL;
    unsigned short* wvb = wkb + (size_t)D_MODEL * D_MODEL;
    unsigned short* wob = wvb + (size_t)D_MODEL * D_MODEL;
    unsigned short* Qb  = wob + (size_t)D_MODEL * D_MODEL;
    unsigned short* Kb  = Qb  + (size_t)MTOT * D_MODEL;
    unsigned short* VtG = Kb  + (size_t)MTOT * D_MODEL;   // V^T [1024][4096]
    unsigned short* Ab  = VtG + (size_t)MTOT * D_MODEL;

    dim3 blk(256);
    cvt_all<<<dim3(2048 + 4 * 512), blk, 0, stream>>>(
        x, w_q, w_k, w_v, w_o, xb, wqb, wkb, wvb, wob);
    // fused QKV projection; z==2 emits V^T = Wv @ x^T directly (VSWAP).
    // Q scale = (1/8) * log2(e) so attention can use exp2.
    gemm_bt<false, true><<<dim3(MTOT / 128, D_MODEL / 128, 3), blk, 0, stream>>>(
        xb, wqb, wkb, wvb, Qb, Kb, VtG, MTOT, D_MODEL, D_MODEL, 0.125f * 1.44269504f);
    // balanced causal flash attention (32x32 MFMA, transposed S/O, split-key waves)
    attn_kernel<<<dim3(BATCH * NHEADS, 32), blk, 0, stream>>>(Qb, Kb, VtG, Ab);
    // output projection -> fp32
    gemm_bt<true, false><<<dim3(MTOT / 128, D_MODEL / 128, 1), blk, 0, stream>>>(
        Ab, wob, wob, wob, out, out, out, MTOT, D_MODEL, D_MODEL, 1.0f);
}